// Round 1
// baseline (2149.646 us; speedup 1.0000x reference)
//
#include <hip/hip_runtime.h>
#include <math.h>

// Problem constants
#define NB 8
#define NT 512           // N_FRAMES
#define NROWS 4096       // NB*NT
#define CI 512           // C_INT
#define DM 1536          // D_MLP
#define CCON 192
#define CSPK 256
#define NW 1024          // N_WINDOW
#define FS 960           // FRAME_SIZE
#define LTOT 491520      // NT*FS
#define CONVW 1984       // FS+NW

// ---------------- spk base: base[b][o] = w_spk@spk + b_spk + b_content + b_f0 + b_energy
__global__ void spkbase_kernel(const float* __restrict__ spk, const float* __restrict__ w_spk,
                               const float* __restrict__ b_spk, const float* __restrict__ b_content,
                               const float* __restrict__ b_f0, const float* __restrict__ b_energy,
                               float* __restrict__ base) {
    int b = blockIdx.x, tid = threadIdx.x;
    __shared__ float s[CSPK];
    if (tid < CSPK) s[tid] = spk[b * CSPK + tid];
    __syncthreads();
    for (int o = tid; o < CI; o += 256) {
        float acc = 0.f;
        for (int c = 0; c < CSPK; ++c) acc = fmaf(w_spk[o * CSPK + c], s[c], acc);
        base[b * CI + o] = acc + b_spk[o] + b_content[o] + b_f0[o] + b_energy[o];
    }
}

// ---------------- content transpose: (B, 192, T) -> ct[(b*T+t)][c]
__global__ void transpose_content(const float* __restrict__ content, float* __restrict__ ct) {
    __shared__ float tile[32][33];
    int b = blockIdx.z, c0 = blockIdx.y * 32, t0 = blockIdx.x * 32;
    int x = threadIdx.x, y = threadIdx.y;
#pragma unroll
    for (int i = 0; i < 32; i += 8)
        tile[y + i][x] = content[((size_t)b * CCON + c0 + y + i) * NT + t0 + x];
    __syncthreads();
#pragma unroll
    for (int i = 0; i < 32; i += 8)
        ct[((size_t)b * NT + t0 + y + i) * CCON + c0 + x] = tile[x][y + i];
}

// ---------------- generic NT GEMM: out[m][o] = epi( sum_k A[m][k]*W[o][k] )
// MODE 0: trunk (+base +w_f0*logf0 +w_energy*energy), 1: +bias,gelu  2: +bias,+residual  3: +bias
#define BK 16
#define TILE 64
template <int MODE>
__global__ __launch_bounds__(256) void gemm_kernel(
    const float* __restrict__ A, const float* __restrict__ W, const float* __restrict__ bias,
    float* __restrict__ out, int K, int NC,
    const float* __restrict__ aux0, const float* __restrict__ aux1, const float* __restrict__ aux2,
    const float* __restrict__ aux3, const float* __restrict__ aux4) {
    __shared__ float As[BK][TILE + 4];
    __shared__ float Ws[BK][TILE + 4];
    int tid = threadIdx.x;
    int tx = tid & 15, ty = tid >> 4;
    int m0 = blockIdx.x * TILE, n0 = blockIdx.y * TILE;
    int lr = tid >> 2, lq = tid & 3;
    const float* Ag = A + (size_t)(m0 + lr) * K + lq * 4;
    const float* Wg = W + (size_t)(n0 + lr) * K + lq * 4;
    float acc[4][4] = {};
    for (int k0 = 0; k0 < K; k0 += BK) {
        float4 av = *(const float4*)(Ag + k0);
        float4 wv = *(const float4*)(Wg + k0);
        As[lq * 4 + 0][lr] = av.x; As[lq * 4 + 1][lr] = av.y;
        As[lq * 4 + 2][lr] = av.z; As[lq * 4 + 3][lr] = av.w;
        Ws[lq * 4 + 0][lr] = wv.x; Ws[lq * 4 + 1][lr] = wv.y;
        Ws[lq * 4 + 2][lr] = wv.z; Ws[lq * 4 + 3][lr] = wv.w;
        __syncthreads();
#pragma unroll
        for (int kk = 0; kk < BK; ++kk) {
            float4 a4 = *(const float4*)&As[kk][ty * 4];
            float4 b4 = *(const float4*)&Ws[kk][tx * 4];
            float aa[4] = {a4.x, a4.y, a4.z, a4.w};
            float bb[4] = {b4.x, b4.y, b4.z, b4.w};
#pragma unroll
            for (int i = 0; i < 4; ++i)
#pragma unroll
                for (int j = 0; j < 4; ++j) acc[i][j] = fmaf(aa[i], bb[j], acc[i][j]);
        }
        __syncthreads();
    }
#pragma unroll
    for (int i = 0; i < 4; ++i) {
        int m = m0 + ty * 4 + i;
        float fv = 0.f, ev = 0.f;
        if (MODE == 0) {
            fv = logf(fmaxf(aux1[m], 0.f) + 1e-6f);
            ev = aux2[m];
        }
        float4 o4;
        float res[4];
#pragma unroll
        for (int j = 0; j < 4; ++j) {
            int o = n0 + tx * 4 + j;
            float v = acc[i][j];
            if (MODE == 0) {
                int b = m >> 9;
                v += aux0[(b << 9) + o] + aux3[o] * fv + aux4[o] * ev;
            } else if (MODE == 1) {
                v += bias[o];
                v = 0.5f * v * (1.f + erff(v * 0.70710678118654752f));
            } else if (MODE == 2) {
                v += bias[o] + aux0[(size_t)m * NC + o];
            } else {
                v += bias[o];
            }
            res[j] = v;
        }
        o4.x = res[0]; o4.y = res[1]; o4.z = res[2]; o4.w = res[3];
        *(float4*)(out + (size_t)m * NC + n0 + tx * 4) = o4;
    }
}

// ---------------- head GEMM: filt[m][w] = sum_{c,k} x[clamp-row][c] * w_out[w][c*7+k] + b_out[w]
__global__ __launch_bounds__(256) void head_gemm(const float* __restrict__ X,
                                                 const float* __restrict__ Wt,
                                                 const float* __restrict__ bias,
                                                 float* __restrict__ out) {
    __shared__ float As[BK][TILE + 4];
    __shared__ float Ws[BK][TILE + 4];
    int tid = threadIdx.x;
    int tx = tid & 15, ty = tid >> 4;
    int m0 = blockIdx.x * TILE, n0 = blockIdx.y * TILE;
    int b = m0 >> 9, tbase = m0 & (NT - 1);
    int kkl = tid & 15, r4 = tid >> 4;
    int lr = tid >> 2, lq = tid & 3;
    const float* Wg = Wt + (size_t)(n0 + lr) * 3584 + lq * 4;
    float acc[4][4] = {};
    for (int k0 = 0; k0 < 3584; k0 += BK) {
        int kabs = k0 + kkl;
        int c = kabs / 7, kq = kabs - c * 7;
#pragma unroll
        for (int q = 0; q < 4; ++q) {
            int mm = r4 * 4 + q;
            int t = tbase + mm;
            int tt = min(max(t + kq - 3, 0), NT - 1);
            As[kkl][mm] = X[((size_t)(b << 9) + tt) * CI + c];
        }
        float4 wv = *(const float4*)(Wg + k0);
        Ws[lq * 4 + 0][lr] = wv.x; Ws[lq * 4 + 1][lr] = wv.y;
        Ws[lq * 4 + 2][lr] = wv.z; Ws[lq * 4 + 3][lr] = wv.w;
        __syncthreads();
#pragma unroll
        for (int kk = 0; kk < BK; ++kk) {
            float4 a4 = *(const float4*)&As[kk][ty * 4];
            float4 b4 = *(const float4*)&Ws[kk][tx * 4];
            float aa[4] = {a4.x, a4.y, a4.z, a4.w};
            float bb[4] = {b4.x, b4.y, b4.z, b4.w};
#pragma unroll
            for (int i = 0; i < 4; ++i)
#pragma unroll
                for (int j = 0; j < 4; ++j) acc[i][j] = fmaf(aa[i], bb[j], acc[i][j]);
        }
        __syncthreads();
    }
#pragma unroll
    for (int i = 0; i < 4; ++i) {
        int m = m0 + ty * 4 + i;
        float4 o4;
        float res[4];
#pragma unroll
        for (int j = 0; j < 4; ++j) {
            int o = n0 + tx * 4 + j;
            res[j] = acc[i][j] + bias[o];
        }
        o4.x = res[0]; o4.y = res[1]; o4.z = res[2]; o4.w = res[3];
        *(float4*)(out + (size_t)m * NW + n0 + tx * 4) = o4;
    }
}

// ---------------- fused depthwise conv (zero pad) + channel LayerNorm; DW=false: LN only
template <bool DW>
__global__ __launch_bounds__(256) void dwln_kernel(const float* __restrict__ X, float* __restrict__ H,
                                                   const float* __restrict__ dw_w,
                                                   const float* __restrict__ dw_b,
                                                   const float* __restrict__ g,
                                                   const float* __restrict__ bb) {
    int n = blockIdx.x;
    int b = n >> 9, t = n & (NT - 1);
    int tid = threadIdx.x;
    float v[2];
#pragma unroll
    for (int h = 0; h < 2; ++h) {
        int c = tid + h * 256;
        float acc;
        if (DW) {
            acc = dw_b[c];
#pragma unroll
            for (int k = 0; k < 7; ++k) {
                int tt = t + k - 3;
                if (tt >= 0 && tt < NT)
                    acc = fmaf(dw_w[c * 7 + k], X[((size_t)(b << 9) + tt) * CI + c], acc);
            }
        } else {
            acc = X[(size_t)n * CI + c];
        }
        v[h] = acc;
    }
    float s1 = v[0] + v[1];
    float s2 = v[0] * v[0] + v[1] * v[1];
    for (int off = 32; off > 0; off >>= 1) {
        s1 += __shfl_down(s1, off);
        s2 += __shfl_down(s2, off);
    }
    __shared__ float r1[4], r2[4];
    int wv = tid >> 6, ln = tid & 63;
    if (ln == 0) { r1[wv] = s1; r2[wv] = s2; }
    __syncthreads();
    if (tid == 0) {
        float t1 = r1[0] + r1[1] + r1[2] + r1[3];
        float t2 = r2[0] + r2[1] + r2[2] + r2[3];
        float mean = t1 * (1.f / CI);
        float var = t2 * (1.f / CI) - mean * mean;
        r1[0] = mean;
        r2[0] = rsqrtf(var + 1e-6f);
    }
    __syncthreads();
    float mean = r1[0], rs = r2[0];
#pragma unroll
    for (int h = 0; h < 2; ++h) {
        int c = tid + h * 256;
        H[(size_t)n * CI + c] = (v[h] - mean) * rs * g[c] + bb[c];
    }
}

// ---------------- per-frame FIR: conv[b,g,u] = sum_j src[g*960+j] * filt[b,g, j-u+1024]
__global__ __launch_bounds__(256) void fir_kernel(const float* __restrict__ source,
                                                  const float* __restrict__ filt,
                                                  float* __restrict__ conv) {
    __shared__ float P[2948];     // padded filter: tap k at P[k+964], zeros elsewhere
    __shared__ float s_src[FS];
    int tid = threadIdx.x;
    int bg = blockIdx.x;
    int b = bg >> 9, g = bg & (NT - 1);
    for (int i = tid; i < 2948; i += 256) P[i] = 0.f;
    __syncthreads();
    {
        float4 fv = ((const float4*)(filt + (size_t)bg * NW))[tid];
        *(float4*)&P[964 + tid * 4] = fv;
    }
    if (tid < 240) {
        float4 sv = ((const float4*)(source + (size_t)b * LTOT + g * FS))[tid];
        *(float4*)&s_src[tid * 4] = sv;
    }
    __syncthreads();
#pragma unroll
    for (int m = 0; m < 2; ++m) {
        int u_base = m * 1024 + tid * 4;
        if (u_base < CONVW) {
            int pbase = 1988 - u_base;     // index of tap (j2 - u_base + 1024) at j2=0
            float r1 = P[pbase - 1], r2 = P[pbase - 2], r3 = P[pbase - 3];
            float a0 = 0.f, a1 = 0.f, a2 = 0.f, a3 = 0.f;
#pragma unroll 4
            for (int j2 = 0; j2 < FS; ++j2) {
                float sv = s_src[j2];
                float vv = P[pbase + j2];
                a0 = fmaf(sv, vv, a0);
                a1 = fmaf(sv, r1, a1);
                a2 = fmaf(sv, r2, a2);
                a3 = fmaf(sv, r3, a3);
                r3 = r2; r2 = r1; r1 = vv;
            }
            float4 o4; o4.x = a0; o4.y = a1; o4.z = a2; o4.w = a3;
            *(float4*)(conv + (size_t)bg * CONVW + u_base) = o4;
        }
    }
}

// ---------------- overlap-add fold
__global__ void fold_kernel(const float* __restrict__ conv, float* __restrict__ out) {
    int b = blockIdx.y;
    int t = blockIdx.x * blockDim.x + threadIdx.x;
    float sum = 0.f;
    int G = (t - 1) / 960;   // t==0 -> 0, reads conv[b,0,0]==0 (harmless)
#pragma unroll
    for (int r = 0; r < 3; ++r) {
        int g = G - r;
        if (g >= 0) {
            int u = t - 960 * g;
            if (u < CONVW) sum += conv[((size_t)(b * NT + g)) * CONVW + u];
        }
    }
    out[(size_t)b * LTOT + t] = sum;
}

extern "C" void kernel_launch(void* const* d_in, const int* in_sizes, int n_in,
                              void* d_out, int out_size, void* d_ws, size_t ws_size,
                              hipStream_t stream) {
    const float* content  = (const float*)d_in[0];
    const float* f0       = (const float*)d_in[1];
    const float* energy   = (const float*)d_in[2];
    const float* spk      = (const float*)d_in[3];
    const float* source   = (const float*)d_in[4];
    const float* w_content= (const float*)d_in[5];
    const float* b_content= (const float*)d_in[6];
    const float* w_spk    = (const float*)d_in[7];
    const float* b_spk    = (const float*)d_in[8];
    const float* w_f0     = (const float*)d_in[9];
    const float* b_f0     = (const float*)d_in[10];
    const float* w_energy = (const float*)d_in[11];
    const float* b_energy = (const float*)d_in[12];
    const float* dw_w     = (const float*)d_in[13];
    const float* dw_b     = (const float*)d_in[14];
    const float* ln_g     = (const float*)d_in[15];
    const float* ln_b     = (const float*)d_in[16];
    const float* pw1_w    = (const float*)d_in[17];
    const float* pw1_b    = (const float*)d_in[18];
    const float* pw2_w    = (const float*)d_in[19];
    const float* pw2_b    = (const float*)d_in[20];
    const float* out_ln_g = (const float*)d_in[21];
    const float* out_ln_b = (const float*)d_in[22];
    const float* w_out    = (const float*)d_in[23];
    const float* b_out    = (const float*)d_in[24];
    float* out = (float*)d_out;

    float* ws = (float*)d_ws;
    // layout (floats): x[2M] | h[2M] | scratch S (ct | hmid | conv, 8.13M) | filt[4M] | base[4k]
    float* x    = ws;                       // 2,097,152
    float* h    = ws + 2097152;             // 2,097,152
    float* S    = ws + 4194304;             // 8,126,464 (ct=786k / hmid=6.29M / conv=8.13M)
    float* filt = ws + 12320768;            // 4,194,304
    float* base = ws + 16515072;            // 4,096     -> total 16,519,168 floats (66 MB)
    float* ct = S;
    float* hmid = S;
    float* conv = S;

    spkbase_kernel<<<NB, 256, 0, stream>>>(spk, w_spk, b_spk, b_content, b_f0, b_energy, base);
    transpose_content<<<dim3(16, 6, NB), dim3(32, 8), 0, stream>>>(content, ct);
    // trunk: x = ct @ w_content^T + base + w_f0*logf0 + w_energy*energy
    gemm_kernel<0><<<dim3(NROWS / TILE, CI / TILE), 256, 0, stream>>>(
        ct, w_content, nullptr, x, CCON, CI, base, f0, energy, w_f0, w_energy);

    for (int i = 0; i < 6; ++i) {
        dwln_kernel<true><<<NROWS, 256, 0, stream>>>(x, h, dw_w + i * CI * 7, dw_b + i * CI,
                                                     ln_g + i * CI, ln_b + i * CI);
        gemm_kernel<1><<<dim3(NROWS / TILE, DM / TILE), 256, 0, stream>>>(
            h, pw1_w + (size_t)i * DM * CI, pw1_b + i * DM, hmid, CI, DM,
            nullptr, nullptr, nullptr, nullptr, nullptr);
        gemm_kernel<2><<<dim3(NROWS / TILE, CI / TILE), 256, 0, stream>>>(
            hmid, pw2_w + (size_t)i * CI * DM, pw2_b + i * CI, x, DM, CI,
            x, nullptr, nullptr, nullptr, nullptr);
    }

    dwln_kernel<false><<<NROWS, 256, 0, stream>>>(x, h, nullptr, nullptr, out_ln_g, out_ln_b);
    head_gemm<<<dim3(NROWS / TILE, NW / TILE), 256, 0, stream>>>(h, w_out, b_out, filt);
    fir_kernel<<<NROWS, 256, 0, stream>>>(source, filt, conv);
    fold_kernel<<<dim3(LTOT / 256, NB), 256, 0, stream>>>(conv, out);
}

// Round 2
// 955.617 us; speedup vs baseline: 2.2495x; 2.2495x over previous
//
#include <hip/hip_runtime.h>
#include <math.h>

// Problem constants
#define NB 8
#define NT 512           // N_FRAMES
#define NROWS 4096       // NB*NT
#define CI 512           // C_INT
#define DM 1536          // D_MLP
#define CCON 192
#define CSPK 256
#define NW 1024          // N_WINDOW
#define FS 960           // FRAME_SIZE
#define LTOT 491520      // NT*FS
#define CONVW 1984       // FS+NW

typedef __bf16 bf16x8 __attribute__((ext_vector_type(8)));
typedef float f32x4 __attribute__((ext_vector_type(4)));
typedef unsigned short ushort;

__device__ __forceinline__ ushort f2bf(float x) {
    union { float f; unsigned u; } v; v.f = x;
    unsigned r = v.u + 0x7fff + ((v.u >> 16) & 1);
    return (ushort)(r >> 16);
}

#define ASYNC_COPY16(g, l) __builtin_amdgcn_global_load_lds( \
    (const __attribute__((address_space(1))) void*)(g), \
    (__attribute__((address_space(3))) void*)(l), 16, 0, 0)

// ---------------- weight fp32 -> bf16 (elementwise, 4/thread)
__global__ void cvt_bf16(const float* __restrict__ in, ushort* __restrict__ out, int n4) {
    int i = blockIdx.x * 256 + threadIdx.x;
    if (i < n4) {
        float4 v = ((const float4*)in)[i];
        ushort4 o; o.x = f2bf(v.x); o.y = f2bf(v.y); o.z = f2bf(v.z); o.w = f2bf(v.w);
        ((ushort4*)out)[i] = o;
    }
}

// ---------------- w_out (NW, CI, 7) -> wk[k][n][c] bf16
__global__ void cvt_wout(const float* __restrict__ w, ushort* __restrict__ wk) {
    int n = blockIdx.x, tid = threadIdx.x;
    __shared__ ushort s[7][512];
#pragma unroll
    for (int h = 0; h < 2; ++h) {
        int c = tid + h * 256;
        const float* p = w + ((size_t)n * 512 + c) * 7;
#pragma unroll
        for (int k = 0; k < 7; ++k) s[k][c] = f2bf(p[k]);
    }
    __syncthreads();
#pragma unroll
    for (int k = 0; k < 7; ++k)
#pragma unroll
        for (int h = 0; h < 2; ++h) {
            int c = tid + h * 256;
            wk[((size_t)k * NW + n) * CI + c] = s[k][c];
        }
}

// ---------------- spk base
__global__ void spkbase_kernel(const float* __restrict__ spk, const float* __restrict__ w_spk,
                               const float* __restrict__ b_spk, const float* __restrict__ b_content,
                               const float* __restrict__ b_f0, const float* __restrict__ b_energy,
                               float* __restrict__ base) {
    int b = blockIdx.x, tid = threadIdx.x;
    __shared__ float s[CSPK];
    if (tid < CSPK) s[tid] = spk[b * CSPK + tid];
    __syncthreads();
    for (int o = tid; o < CI; o += 256) {
        float acc = 0.f;
        for (int c = 0; c < CSPK; ++c) acc = fmaf(w_spk[o * CSPK + c], s[c], acc);
        base[b * CI + o] = acc + b_spk[o] + b_content[o] + b_f0[o] + b_energy[o];
    }
}

// ---------------- content transpose: (B, 192, T) -> ct[(b*T+t)][c]
__global__ void transpose_content(const float* __restrict__ content, float* __restrict__ ct) {
    __shared__ float tile[32][33];
    int b = blockIdx.z, c0 = blockIdx.y * 32, t0 = blockIdx.x * 32;
    int x = threadIdx.x, y = threadIdx.y;
#pragma unroll
    for (int i = 0; i < 32; i += 8)
        tile[y + i][x] = content[((size_t)b * CCON + c0 + y + i) * NT + t0 + x];
    __syncthreads();
#pragma unroll
    for (int i = 0; i < 32; i += 8)
        ct[((size_t)b * NT + t0 + y + i) * CCON + c0 + x] = tile[x][y + i];
}

// ---------------- fp32 trunk GEMM (K=192, small)
#define BK 16
#define TILE 64
__global__ __launch_bounds__(256) void gemm_trunk(
    const float* __restrict__ A, const float* __restrict__ W, float* __restrict__ out,
    const float* __restrict__ base, const float* __restrict__ f0, const float* __restrict__ energy,
    const float* __restrict__ w_f0, const float* __restrict__ w_energy) {
    __shared__ float As[BK][TILE + 4];
    __shared__ float Ws[BK][TILE + 4];
    int tid = threadIdx.x;
    int tx = tid & 15, ty = tid >> 4;
    int m0 = blockIdx.x * TILE, n0 = blockIdx.y * TILE;
    int lr = tid >> 2, lq = tid & 3;
    const float* Ag = A + (size_t)(m0 + lr) * CCON + lq * 4;
    const float* Wg = W + (size_t)(n0 + lr) * CCON + lq * 4;
    float acc[4][4] = {};
    for (int k0 = 0; k0 < CCON; k0 += BK) {
        float4 av = *(const float4*)(Ag + k0);
        float4 wv = *(const float4*)(Wg + k0);
        As[lq * 4 + 0][lr] = av.x; As[lq * 4 + 1][lr] = av.y;
        As[lq * 4 + 2][lr] = av.z; As[lq * 4 + 3][lr] = av.w;
        Ws[lq * 4 + 0][lr] = wv.x; Ws[lq * 4 + 1][lr] = wv.y;
        Ws[lq * 4 + 2][lr] = wv.z; Ws[lq * 4 + 3][lr] = wv.w;
        __syncthreads();
#pragma unroll
        for (int kk = 0; kk < BK; ++kk) {
            float4 a4 = *(const float4*)&As[kk][ty * 4];
            float4 b4 = *(const float4*)&Ws[kk][tx * 4];
            float aa[4] = {a4.x, a4.y, a4.z, a4.w};
            float bb[4] = {b4.x, b4.y, b4.z, b4.w};
#pragma unroll
            for (int i = 0; i < 4; ++i)
#pragma unroll
                for (int j = 0; j < 4; ++j) acc[i][j] = fmaf(aa[i], bb[j], acc[i][j]);
        }
        __syncthreads();
    }
#pragma unroll
    for (int i = 0; i < 4; ++i) {
        int m = m0 + ty * 4 + i;
        float fv = logf(fmaxf(f0[m], 0.f) + 1e-6f);
        float ev = energy[m];
        int b = m >> 9;
        float4 o4;
        float res[4];
#pragma unroll
        for (int j = 0; j < 4; ++j) {
            int o = n0 + tx * 4 + j;
            res[j] = acc[i][j] + base[(b << 9) + o] + w_f0[o] * fv + w_energy[o] * ev;
        }
        o4.x = res[0]; o4.y = res[1]; o4.z = res[2]; o4.w = res[3];
        *(float4*)(out + (size_t)m * CI + n0 + tx * 4) = o4;
    }
}

// ---------------- bf16 MFMA GEMM: out[m][n] = epi( sum_k A[m][k] * W[n][k] )
// MODE 1: +bias, gelu, bf16 out. MODE 2: +bias +residual(fp32), fp32 out.
// TM x TN tile, BK=32, 4 waves in 2x2; wave computes (TM/2)x(TN/2).
template <int MODE, int TM, int TN>
__global__ __launch_bounds__(256) void gemm_mfma(
    const ushort* __restrict__ A, const ushort* __restrict__ W,
    const float* __restrict__ bias, void* __restrict__ outp,
    const float* __restrict__ res, int K, int NC) {
    constexpr int MI = TM / 32, NI = TN / 32;
    __shared__ ushort As[TM * 32];
    __shared__ ushort Bs[TN * 32];
    int tid = threadIdx.x;
    int wave = tid >> 6, lane = tid & 63;
    int m0 = blockIdx.x * TM, n0 = blockIdx.y * TN;
    // staging: each wave stages TM/4 rows of A (and TN/4 of B), 16 rows / issue
    int srow = lane >> 2, schunk = lane & 3;
    const ushort* Ag = A + (size_t)(m0 + wave * (TM / 4) + srow) * K + schunk * 8;
    const ushort* Wg = W + (size_t)(n0 + wave * (TN / 4) + srow) * K + schunk * 8;
    ushort* Al = &As[(wave * (TM / 4)) * 32];
    ushort* Bl = &Bs[(wave * (TN / 4)) * 32];
    int lm = lane & 15, kq = lane >> 4;  // fragment coords
    int wm = wave & 1, wn = wave >> 1;
    f32x4 acc[MI][NI];
#pragma unroll
    for (int i = 0; i < MI; ++i)
#pragma unroll
        for (int j = 0; j < NI; ++j) acc[i][j] = (f32x4)0.f;

    for (int k0 = 0; k0 < K; k0 += 32) {
#pragma unroll
        for (int i = 0; i < TM / 64; ++i)
            ASYNC_COPY16(Ag + k0 + (size_t)i * 16 * K, Al + i * 16 * 32);
#pragma unroll
        for (int i = 0; i < TN / 64; ++i)
            ASYNC_COPY16(Wg + k0 + (size_t)i * 16 * K, Bl + i * 16 * 32);
        __syncthreads();
        bf16x8 af[MI], bf[NI];
#pragma unroll
        for (int i = 0; i < MI; ++i)
            af[i] = *(const bf16x8*)&As[(wm * (TM / 2) + i * 16 + lm) * 32 + kq * 8];
#pragma unroll
        for (int j = 0; j < NI; ++j)
            bf[j] = *(const bf16x8*)&Bs[(wn * (TN / 2) + j * 16 + lm) * 32 + kq * 8];
#pragma unroll
        for (int i = 0; i < MI; ++i)
#pragma unroll
            for (int j = 0; j < NI; ++j)
                acc[i][j] = __builtin_amdgcn_mfma_f32_16x16x32_bf16(af[i], bf[j], acc[i][j], 0, 0, 0);
        __syncthreads();
    }
#pragma unroll
    for (int i = 0; i < MI; ++i)
#pragma unroll
        for (int j = 0; j < NI; ++j) {
            int col = n0 + wn * (TN / 2) + j * 16 + lm;
            float bv = bias[col];
#pragma unroll
            for (int r = 0; r < 4; ++r) {
                int row = m0 + wm * (TM / 2) + i * 16 + kq * 4 + r;
                float v = acc[i][j][r] + bv;
                if (MODE == 1) {
                    v = 0.5f * v * (1.f + erff(v * 0.70710678118654752f));
                    ((ushort*)outp)[(size_t)row * NC + col] = f2bf(v);
                } else {
                    v += res[(size_t)row * NC + col];
                    ((float*)outp)[(size_t)row * NC + col] = v;
                }
            }
        }
}

// ---------------- head: filt[m][n] = sum_{k,c} h[b, clamp(t+k-3)][c] * wk[k][n][c] + b_out[n]
__global__ __launch_bounds__(256) void head_mfma(
    const ushort* __restrict__ H, const ushort* __restrict__ WK,
    const float* __restrict__ bias, float* __restrict__ out) {
    constexpr int TM = 128, TN = 128, MI = 4, NI = 4;
    __shared__ ushort As[TM * 32];
    __shared__ ushort Bs[TN * 32];
    int tid = threadIdx.x;
    int wave = tid >> 6, lane = tid & 63;
    int m0 = blockIdx.x * TM, n0 = blockIdx.y * TN;
    int b = m0 >> 9, tbase = m0 & (NT - 1);
    int srow = lane >> 2, schunk = lane & 3;
    ushort* Al = &As[(wave * 32) * 32];
    ushort* Bl = &Bs[(wave * 32) * 32];
    int lm = lane & 15, kq = lane >> 4;
    int wm = wave & 1, wn = wave >> 1;
    f32x4 acc[MI][NI];
#pragma unroll
    for (int i = 0; i < MI; ++i)
#pragma unroll
        for (int j = 0; j < NI; ++j) acc[i][j] = (f32x4)0.f;

    for (int k = 0; k < 7; ++k) {
        // per-lane clamped A row addresses for the two 16-row issues
        const ushort* ag[2];
#pragma unroll
        for (int i = 0; i < 2; ++i) {
            int t = tbase + wave * 32 + i * 16 + srow + k - 3;
            t = min(max(t, 0), NT - 1);
            ag[i] = H + ((size_t)(b << 9) + t) * CI + schunk * 8;
        }
        const ushort* wg = WK + ((size_t)k * NW + n0 + wave * 32 + srow) * CI + schunk * 8;
        for (int c0 = 0; c0 < CI; c0 += 32) {
#pragma unroll
            for (int i = 0; i < 2; ++i)
                ASYNC_COPY16(ag[i] + c0, Al + i * 16 * 32);
#pragma unroll
            for (int i = 0; i < 2; ++i)
                ASYNC_COPY16(wg + c0 + (size_t)i * 16 * CI, Bl + i * 16 * 32);
            __syncthreads();
            bf16x8 af[MI], bf[NI];
#pragma unroll
            for (int i = 0; i < MI; ++i)
                af[i] = *(const bf16x8*)&As[(wm * 64 + i * 16 + lm) * 32 + kq * 8];
#pragma unroll
            for (int j = 0; j < NI; ++j)
                bf[j] = *(const bf16x8*)&Bs[(wn * 64 + j * 16 + lm) * 32 + kq * 8];
#pragma unroll
            for (int i = 0; i < MI; ++i)
#pragma unroll
                for (int j = 0; j < NI; ++j)
                    acc[i][j] = __builtin_amdgcn_mfma_f32_16x16x32_bf16(af[i], bf[j], acc[i][j], 0, 0, 0);
            __syncthreads();
        }
    }
#pragma unroll
    for (int i = 0; i < MI; ++i)
#pragma unroll
        for (int j = 0; j < NI; ++j) {
            int col = n0 + wn * 64 + j * 16 + lm;
            float bv = bias[col];
#pragma unroll
            for (int r = 0; r < 4; ++r) {
                int row = m0 + wm * 64 + i * 16 + kq * 4 + r;
                out[(size_t)row * NW + col] = acc[i][j][r] + bv;
            }
        }
}

// ---------------- fused depthwise conv (zero pad) + channel LayerNorm -> bf16; DW=false: LN only
template <bool DW>
__global__ __launch_bounds__(256) void dwln_kernel(const float* __restrict__ X, ushort* __restrict__ H,
                                                   const float* __restrict__ dw_w,
                                                   const float* __restrict__ dw_b,
                                                   const float* __restrict__ g,
                                                   const float* __restrict__ bb) {
    int n = blockIdx.x;
    int b = n >> 9, t = n & (NT - 1);
    int tid = threadIdx.x;
    float v[2];
#pragma unroll
    for (int h = 0; h < 2; ++h) {
        int c = tid + h * 256;
        float acc;
        if (DW) {
            acc = dw_b[c];
#pragma unroll
            for (int k = 0; k < 7; ++k) {
                int tt = t + k - 3;
                if (tt >= 0 && tt < NT)
                    acc = fmaf(dw_w[c * 7 + k], X[((size_t)(b << 9) + tt) * CI + c], acc);
            }
        } else {
            acc = X[(size_t)n * CI + c];
        }
        v[h] = acc;
    }
    float s1 = v[0] + v[1];
    float s2 = v[0] * v[0] + v[1] * v[1];
    for (int off = 32; off > 0; off >>= 1) {
        s1 += __shfl_down(s1, off);
        s2 += __shfl_down(s2, off);
    }
    __shared__ float r1[4], r2[4];
    int wv = tid >> 6, ln = tid & 63;
    if (ln == 0) { r1[wv] = s1; r2[wv] = s2; }
    __syncthreads();
    if (tid == 0) {
        float t1 = r1[0] + r1[1] + r1[2] + r1[3];
        float t2 = r2[0] + r2[1] + r2[2] + r2[3];
        float mean = t1 * (1.f / CI);
        float var = t2 * (1.f / CI) - mean * mean;
        r1[0] = mean;
        r2[0] = rsqrtf(var + 1e-6f);
    }
    __syncthreads();
    float mean = r1[0], rs = r2[0];
#pragma unroll
    for (int h = 0; h < 2; ++h) {
        int c = tid + h * 256;
        H[(size_t)n * CI + c] = f2bf((v[h] - mean) * rs * g[c] + bb[c]);
    }
}

// ---------------- per-frame FIR
__global__ __launch_bounds__(256) void fir_kernel(const float* __restrict__ source,
                                                  const float* __restrict__ filt,
                                                  float* __restrict__ conv) {
    __shared__ float P[2948];
    __shared__ float s_src[FS];
    int tid = threadIdx.x;
    int bg = blockIdx.x;
    int b = bg >> 9, g = bg & (NT - 1);
    for (int i = tid; i < 2948; i += 256) P[i] = 0.f;
    __syncthreads();
    {
        float4 fv = ((const float4*)(filt + (size_t)bg * NW))[tid];
        *(float4*)&P[964 + tid * 4] = fv;
    }
    if (tid < 240) {
        float4 sv = ((const float4*)(source + (size_t)b * LTOT + g * FS))[tid];
        *(float4*)&s_src[tid * 4] = sv;
    }
    __syncthreads();
#pragma unroll
    for (int m = 0; m < 2; ++m) {
        int u_base = m * 1024 + tid * 4;
        if (u_base < CONVW) {
            int pbase = 1988 - u_base;
            float r1 = P[pbase - 1], r2 = P[pbase - 2], r3 = P[pbase - 3];
            float a0 = 0.f, a1 = 0.f, a2 = 0.f, a3 = 0.f;
#pragma unroll 4
            for (int j2 = 0; j2 < FS; ++j2) {
                float sv = s_src[j2];
                float vv = P[pbase + j2];
                a0 = fmaf(sv, vv, a0);
                a1 = fmaf(sv, r1, a1);
                a2 = fmaf(sv, r2, a2);
                a3 = fmaf(sv, r3, a3);
                r3 = r2; r2 = r1; r1 = vv;
            }
            float4 o4; o4.x = a0; o4.y = a1; o4.z = a2; o4.w = a3;
            *(float4*)(conv + (size_t)bg * CONVW + u_base) = o4;
        }
    }
}

// ---------------- overlap-add fold
__global__ void fold_kernel(const float* __restrict__ conv, float* __restrict__ out) {
    int b = blockIdx.y;
    int t = blockIdx.x * blockDim.x + threadIdx.x;
    float sum = 0.f;
    int G = (t - 1) / 960;
#pragma unroll
    for (int r = 0; r < 3; ++r) {
        int g = G - r;
        if (g >= 0) {
            int u = t - 960 * g;
            if (u < CONVW) sum += conv[((size_t)(b * NT + g)) * CONVW + u];
        }
    }
    out[(size_t)b * LTOT + t] = sum;
}

extern "C" void kernel_launch(void* const* d_in, const int* in_sizes, int n_in,
                              void* d_out, int out_size, void* d_ws, size_t ws_size,
                              hipStream_t stream) {
    const float* content  = (const float*)d_in[0];
    const float* f0       = (const float*)d_in[1];
    const float* energy   = (const float*)d_in[2];
    const float* spk      = (const float*)d_in[3];
    const float* source   = (const float*)d_in[4];
    const float* w_content= (const float*)d_in[5];
    const float* b_content= (const float*)d_in[6];
    const float* w_spk    = (const float*)d_in[7];
    const float* b_spk    = (const float*)d_in[8];
    const float* w_f0     = (const float*)d_in[9];
    const float* b_f0     = (const float*)d_in[10];
    const float* w_energy = (const float*)d_in[11];
    const float* b_energy = (const float*)d_in[12];
    const float* dw_w     = (const float*)d_in[13];
    const float* dw_b     = (const float*)d_in[14];
    const float* ln_g     = (const float*)d_in[15];
    const float* ln_b     = (const float*)d_in[16];
    const float* pw1_w    = (const float*)d_in[17];
    const float* pw1_b    = (const float*)d_in[18];
    const float* pw2_w    = (const float*)d_in[19];
    const float* pw2_b    = (const float*)d_in[20];
    const float* out_ln_g = (const float*)d_in[21];
    const float* out_ln_b = (const float*)d_in[22];
    const float* w_out    = (const float*)d_in[23];
    const float* b_out    = (const float*)d_in[24];
    float* out = (float*)d_out;

    float* ws = (float*)d_ws;
    // layout (float offsets):
    float*  x    = ws;                              // 2,097,152 f
    float*  base = ws + 2097152;                    // 4,096 f
    float*  ct   = ws + 2101248;                    // 786,432 f
    float*  filt = ws + 2887680;                    // 4,194,304 f
    ushort* h    = (ushort*)(ws + 7081984);         // 2,097,152 bf16 (1,048,576 f)
    // S region at float off 8,130,560 (overlaid: weights+hmid, then conv)
    ushort* pw1w = (ushort*)(ws + 8130560);         // 4,718,592 bf16 (2,359,296 f)
    ushort* pw2w = (ushort*)(ws + 10489856);        // 4,718,592 bf16 (2,359,296 f)
    ushort* wk   = (ushort*)(ws + 12849152);        // 3,670,016 bf16 (1,835,008 f)
    ushort* hmid = (ushort*)(ws + 14684160);        // 6,291,456 bf16 (3,145,728 f)
    float*  conv = ws + 8130560;                    // 8,126,464 f (after head_mfma done)
    // total: 17,829,888 floats = 71.3 MB

    // weight conversions + small prep (independent)
    cvt_bf16<<<4608, 256, 0, stream>>>(pw1_w, pw1w, 1179648);
    cvt_bf16<<<4608, 256, 0, stream>>>(pw2_w, pw2w, 1179648);
    cvt_wout<<<NW, 256, 0, stream>>>(w_out, wk);
    spkbase_kernel<<<NB, 256, 0, stream>>>(spk, w_spk, b_spk, b_content, b_f0, b_energy, base);
    transpose_content<<<dim3(16, 6, NB), dim3(32, 8), 0, stream>>>(content, ct);

    // trunk (fp32): x = ct @ w_content^T + base + w_f0*logf0 + w_energy*energy
    gemm_trunk<<<dim3(NROWS / TILE, CI / TILE), 256, 0, stream>>>(
        ct, w_content, x, base, f0, energy, w_f0, w_energy);

    for (int i = 0; i < 6; ++i) {
        dwln_kernel<true><<<NROWS, 256, 0, stream>>>(x, h, dw_w + i * CI * 7, dw_b + i * CI,
                                                     ln_g + i * CI, ln_b + i * CI);
        gemm_mfma<1, 128, 128><<<dim3(NROWS / 128, DM / 128), 256, 0, stream>>>(
            h, pw1w + (size_t)i * DM * CI, pw1_b + i * DM, hmid, nullptr, CI, DM);
        gemm_mfma<2, 128, 64><<<dim3(NROWS / 128, CI / 64), 256, 0, stream>>>(
            hmid, pw2w + (size_t)i * CI * DM, pw2_b + i * CI, x, x, DM, CI);
    }

    dwln_kernel<false><<<NROWS, 256, 0, stream>>>(x, h, nullptr, nullptr, out_ln_g, out_ln_b);
    head_mfma<<<dim3(NROWS / 128, NW / 128), 256, 0, stream>>>(h, wk, b_out, filt);
    fir_kernel<<<NROWS, 256, 0, stream>>>(source, filt, conv);
    fold_kernel<<<dim3(LTOT / 256, NB), 256, 0, stream>>>(conv, out);
}